// Round 2
// baseline (19497.815 us; speedup 1.0000x reference)
//
#include <hip/hip_runtime.h>
#include <math.h>

#define B_ 32
#define T_ 512
#define U_ 64
#define V_ 32000
#define H_ 512
#define E_ 512
#define GRIDB 512   // recurrence grid: 2 blocks/CU on 256 CUs, co-resident by capacity

typedef __attribute__((ext_vector_type(8))) short bf16x8;
typedef __attribute__((ext_vector_type(4))) float f32x4;

// ---------------- embedding gather ----------------
__global__ void embed_kernel(const int* __restrict__ tok, const float* __restrict__ table,
                             float* __restrict__ out) {
  int row = blockIdx.x;                    // b*U + u
  int t = tok[row];
  const float4* src = (const float4*)(table + (size_t)t * H_);
  float4* dst = (float4*)(out + (size_t)row * H_);
  dst[threadIdx.x] = src[threadIdx.x];
}

__global__ void zero_counter(unsigned* c) { if (threadIdx.x == 0) *c = 0u; }

// ---------------- fp32 GEMM (enc_proj + fallback logits): C=A*Bm^T+bias ----------------
__global__ __launch_bounds__(256) void gemm_abt(
    const float* __restrict__ A, const float* __restrict__ Bm,
    const float* __restrict__ bias, float* __restrict__ C, int N, int K) {
  __shared__ float As[8][128];
  __shared__ float Bs[8][128];
  int tid = threadIdx.x;
  int n0 = blockIdx.x * 128, m0 = blockIdx.y * 128;
  int lr = tid >> 1;
  int lk = (tid & 1) * 4;
  const float* Ap = A + (size_t)(m0 + lr) * K + lk;
  const float* Bp = Bm + (size_t)(n0 + lr) * K + lk;
  int tx = tid & 15, ty = tid >> 4;
  float acc[8][8];
#pragma unroll
  for (int i = 0; i < 8; i++)
#pragma unroll
    for (int j = 0; j < 8; j++) acc[i][j] = 0.f;

  for (int k0 = 0; k0 < K; k0 += 8) {
    float4 av = *(const float4*)(Ap + k0);
    float4 bv = *(const float4*)(Bp + k0);
    __syncthreads();
    As[lk + 0][lr] = av.x; As[lk + 1][lr] = av.y; As[lk + 2][lr] = av.z; As[lk + 3][lr] = av.w;
    Bs[lk + 0][lr] = bv.x; Bs[lk + 1][lr] = bv.y; Bs[lk + 2][lr] = bv.z; Bs[lk + 3][lr] = bv.w;
    __syncthreads();
#pragma unroll
    for (int kk = 0; kk < 8; kk++) {
      float a[8], b[8];
      *(float4*)&a[0] = *(const float4*)&As[kk][ty * 4];
      *(float4*)&a[4] = *(const float4*)&As[kk][ty * 4 + 64];
      *(float4*)&b[0] = *(const float4*)&Bs[kk][tx * 4];
      *(float4*)&b[4] = *(const float4*)&Bs[kk][tx * 4 + 64];
#pragma unroll
      for (int i = 0; i < 8; i++)
#pragma unroll
        for (int j = 0; j < 8; j++) acc[i][j] = fmaf(a[i], b[j], acc[i][j]);
    }
  }
  float bb[8] = {0, 0, 0, 0, 0, 0, 0, 0};
  if (bias) {
    *(float4*)&bb[0] = *(const float4*)&bias[n0 + tx * 4];
    *(float4*)&bb[4] = *(const float4*)&bias[n0 + tx * 4 + 64];
  }
#pragma unroll
  for (int i = 0; i < 8; i++) {
    int m = m0 + ty * 4 + (i & 3) + (i >> 2) * 64;
    float* Crow = C + (size_t)m * N + n0;
    *(float4*)(Crow + tx * 4) = make_float4(acc[i][0] + bb[0], acc[i][1] + bb[1], acc[i][2] + bb[2], acc[i][3] + bb[3]);
    *(float4*)(Crow + tx * 4 + 64) = make_float4(acc[i][4] + bb[4], acc[i][5] + bb[5], acc[i][6] + bb[6], acc[i][7] + bb[7]);
  }
}

// ---------------- persistent recurrence: 64 steps, custom grid barrier ----------------
__device__ __forceinline__ void grid_bar(unsigned* cnt, int& gen, int tid) {
  __syncthreads();
  if (tid == 0) {
    __threadfence();                     // release my writes device-wide
    atomicAdd(cnt, 1u);
    gen++;
    unsigned tgt = (unsigned)gen * GRIDB;
    while (__hip_atomic_load(cnt, __ATOMIC_RELAXED, __HIP_MEMORY_SCOPE_AGENT) < tgt) {
      __builtin_amdgcn_s_sleep(2);
    }
    __threadfence();                     // acquire others' writes
  }
  __syncthreads();
}

__global__ __launch_bounds__(256, 2) void recurrence(
    const float* __restrict__ enc_proj, const float* __restrict__ enc_out,
    const int* __restrict__ lens, const float* __restrict__ embedded,
    const float* __restrict__ W_ih0, const float* __restrict__ W_hh0,
    const float* __restrict__ b_ih0, const float* __restrict__ b_hh0,
    const float* __restrict__ W_ih1, const float* __restrict__ W_hh1,
    const float* __restrict__ b_ih1, const float* __restrict__ b_hh1,
    float* __restrict__ X, float* __restrict__ scores,
    float* __restrict__ hstate, unsigned* __restrict__ cnt) {
  int bid = blockIdx.x, tid = threadIdx.x;
  int gen = 0;
  __shared__ float q[512];
  __shared__ float p[512];
  __shared__ float red2[256];
  __shared__ float Wr[1024], Wz[1024], Wn[1024], Vr[512], Vz[512], Vn[512];
  __shared__ float Ur[512], Uz[512], Un[512], Tr[512], Tz[512], Tn[512];
  __shared__ float red4[4][256];

  float* h0 = hstate;             // [2][32][512]
  float* h1 = hstate + 32768;     // [2][32][512]

  // zero hidden state (both ping-pong buffers)
  int zi = bid * 256 + tid;
  if (zi < 65536) hstate[zi] = 0.f;
  grid_bar(cnt, gen, tid);

  int sb = bid >> 4;              // batch for S1/S2 (0..31)
  int schunk = bid & 15;          // t-chunk / e-chunk (0..15)
  int len = lens[sb];
  int j = bid;                    // GRU output unit (0..511)

  for (int u = 0; u < U_; u++) {
    int cur = u & 1, nxt = cur ^ 1;
    float* h0c = h0 + cur * 16384; float* h0n = h0 + nxt * 16384;
    float* h1c = h1 + cur * 16384; float* h1n = h1 + nxt * 16384;

    // ---- S1: scores[sb][t] for t in [schunk*32, +32) ----
    {
      const float* qsrc = (u == 0) ? (embedded + ((size_t)sb * U_) * H_) : (h1c + sb * H_);
      q[tid] = qsrc[tid]; q[tid + 256] = qsrc[tid + 256];
      __syncthreads();
      int w = tid >> 6, l = tid & 63;
#pragma unroll
      for (int i = 0; i < 8; i++) {
        int t = schunk * 32 + w * 8 + i;
        float acc = 0.f;
        if (t < len) {
          const float* row = enc_proj + ((size_t)sb * T_ + t) * H_;
#pragma unroll
          for (int jj = 0; jj < 8; jj++) acc = fmaf(row[l + 64 * jj], q[l + 64 * jj], acc);
#pragma unroll
          for (int off = 32; off; off >>= 1) acc += __shfl_xor(acc, off, 64);
        }
        if (l == 0) scores[sb * T_ + t] = (t < len) ? acc : -INFINITY;
      }
    }
    grid_bar(cnt, gen, tid);

    // ---- S2: softmax (redundant per block) + context e-slice -> X[:,512+e] ----
    {
      float v1 = scores[sb * T_ + tid], v2 = scores[sb * T_ + 256 + tid];
      red2[tid] = fmaxf(v1, v2);
      __syncthreads();
      for (int s = 128; s; s >>= 1) { if (tid < s) red2[tid] = fmaxf(red2[tid], red2[tid + s]); __syncthreads(); }
      float M = red2[0];
      __syncthreads();
      float e1 = __expf(v1 - M), e2 = __expf(v2 - M);   // -inf -> 0
      red2[tid] = e1 + e2;
      __syncthreads();
      for (int s = 128; s; s >>= 1) { if (tid < s) red2[tid] += red2[tid + s]; __syncthreads(); }
      float inv = 1.f / red2[0];
      __syncthreads();
      p[tid] = e1 * inv; p[tid + 256] = e2 * inv;
      __syncthreads();
      int e = schunk * 32 + (tid & 31), ts = tid >> 5;
      float acc = 0.f;
      const float* eo = enc_out + (size_t)sb * T_ * E_ + e;
      for (int t = ts; t < len; t += 8) acc = fmaf(p[t], eo[(size_t)t * E_], acc);
      red2[tid] = acc;
      __syncthreads();
      if (tid < 32) {
        float c = 0.f;
#pragma unroll
        for (int r = 0; r < 8; r++) c += red2[tid + 32 * r];
        X[((size_t)sb * U_ + u) * 1024 + 512 + schunk * 32 + tid] = c;
      }
    }
    grid_bar(cnt, gen, tid);

    // ---- S3: GRU0 output unit j, all 32 batches ----
    {
      for (int k = tid; k < 1024; k += 256) {
        Wr[k] = W_ih0[(size_t)j * 1024 + k];
        Wz[k] = W_ih0[((size_t)j + 512) * 1024 + k];
        Wn[k] = W_ih0[((size_t)j + 1024) * 1024 + k];
      }
      for (int k = tid; k < 512; k += 256) {
        Vr[k] = W_hh0[(size_t)j * 512 + k];
        Vz[k] = W_hh0[((size_t)j + 512) * 512 + k];
        Vn[k] = W_hh0[((size_t)j + 1024) * 512 + k];
      }
      __syncthreads();
      int bb = tid >> 3, s = tid & 7;
      const float* xe = embedded + ((size_t)bb * U_ + u) * H_;
      const float* xc = X + ((size_t)bb * U_ + u) * 1024;  // ctx lives at [512,1024)
      float ar = 0, az = 0, ain = 0, ahn = 0;
      if (s < 4) {
        for (int k = s * 128; k < s * 128 + 128; k++) {
          float xv = xe[k]; ar = fmaf(Wr[k], xv, ar); az = fmaf(Wz[k], xv, az); ain = fmaf(Wn[k], xv, ain);
        }
      } else {
        for (int k = s * 128; k < s * 128 + 128; k++) {
          float xv = xc[k]; ar = fmaf(Wr[k], xv, ar); az = fmaf(Wz[k], xv, az); ain = fmaf(Wn[k], xv, ain);
        }
      }
      const float* hp = h0c + bb * H_;
      for (int k = s * 64; k < s * 64 + 64; k++) {
        float hv = hp[k]; ar = fmaf(Vr[k], hv, ar); az = fmaf(Vz[k], hv, az); ahn = fmaf(Vn[k], hv, ahn);
      }
      red4[0][tid] = ar; red4[1][tid] = az; red4[2][tid] = ain; red4[3][tid] = ahn;
      __syncthreads();
      if (tid < 32) {
        float r = 0, z = 0, in_ = 0, hn = 0;
#pragma unroll
        for (int q2 = 0; q2 < 8; q2++) {
          r += red4[0][tid * 8 + q2]; z += red4[1][tid * 8 + q2];
          in_ += red4[2][tid * 8 + q2]; hn += red4[3][tid * 8 + q2];
        }
        r += b_ih0[j] + b_hh0[j];
        z += b_ih0[512 + j] + b_hh0[512 + j];
        float rg = 1.f / (1.f + __expf(-r));
        float zg = 1.f / (1.f + __expf(-z));
        float n = tanhf(in_ + b_ih0[1024 + j] + rg * (hn + b_hh0[1024 + j]));
        h0n[tid * H_ + j] = (1.f - zg) * n + zg * h0c[tid * H_ + j];
      }
    }
    grid_bar(cnt, gen, tid);

    // ---- S4: GRU1 output unit j; writes h1 and X[:,0:512] ----
    {
      for (int k = tid; k < 512; k += 256) {
        Ur[k] = W_ih1[(size_t)j * 512 + k];
        Uz[k] = W_ih1[((size_t)j + 512) * 512 + k];
        Un[k] = W_ih1[((size_t)j + 1024) * 512 + k];
        Tr[k] = W_hh1[(size_t)j * 512 + k];
        Tz[k] = W_hh1[((size_t)j + 512) * 512 + k];
        Tn[k] = W_hh1[((size_t)j + 1024) * 512 + k];
      }
      __syncthreads();
      int bb = tid >> 3, s = tid & 7;
      const float* xp = h0n + bb * H_;
      const float* hp = h1c + bb * H_;
      float ar = 0, az = 0, ain = 0, ahn = 0;
      for (int k = s * 64; k < s * 64 + 64; k++) {
        float xv = xp[k]; ar = fmaf(Ur[k], xv, ar); az = fmaf(Uz[k], xv, az); ain = fmaf(Un[k], xv, ain);
        float hv = hp[k]; ar = fmaf(Tr[k], hv, ar); az = fmaf(Tz[k], hv, az); ahn = fmaf(Tn[k], hv, ahn);
      }
      red4[0][tid] = ar; red4[1][tid] = az; red4[2][tid] = ain; red4[3][tid] = ahn;
      __syncthreads();
      if (tid < 32) {
        float r = 0, z = 0, in_ = 0, hn = 0;
#pragma unroll
        for (int q2 = 0; q2 < 8; q2++) {
          r += red4[0][tid * 8 + q2]; z += red4[1][tid * 8 + q2];
          in_ += red4[2][tid * 8 + q2]; hn += red4[3][tid * 8 + q2];
        }
        r += b_ih1[j] + b_hh1[j];
        z += b_ih1[512 + j] + b_hh1[512 + j];
        float rg = 1.f / (1.f + __expf(-r));
        float zg = 1.f / (1.f + __expf(-z));
        float n = tanhf(in_ + b_ih1[1024 + j] + rg * (hn + b_hh1[1024 + j]));
        float ho = (1.f - zg) * n + zg * h1c[tid * H_ + j];
        h1n[tid * H_ + j] = ho;
        X[((size_t)tid * U_ + u) * 1024 + j] = ho;
      }
    }
    grid_bar(cnt, gen, tid);
  }
}

// ---------------- fp32 -> bf16 (RNE) ----------------
__device__ __forceinline__ unsigned short cvt_bf(float f) {
  unsigned int x = __float_as_uint(f);
  unsigned int r = x + 0x7fffu + ((x >> 16) & 1u);
  return (unsigned short)(r >> 16);
}

__global__ __launch_bounds__(256) void f2bf(const float* __restrict__ in,
                                            unsigned short* __restrict__ out, int n) {
  int i = 4 * (blockIdx.x * 256 + threadIdx.x);
  if (i < n) {
    float4 v = *(const float4*)(in + i);
    ushort4 o;
    o.x = cvt_bf(v.x); o.y = cvt_bf(v.y); o.z = cvt_bf(v.z); o.w = cvt_bf(v.w);
    *(ushort4*)(out + i) = o;
  }
}

// ---------------- bf16 MFMA GEMM: C[m,n] = A[m,:].Bm[n,:] + bias[n] ----------------
// 128x128 tile, BK=32, 256 threads (4 waves 2x2), mfma_f32_16x16x32_bf16.
__global__ __launch_bounds__(256) void gemm_bf16(
    const unsigned short* __restrict__ A, const unsigned short* __restrict__ Bm,
    const float* __restrict__ bias, float* __restrict__ C, int N, int K) {
  __shared__ unsigned short As[128 * 40];  // row stride 40 (pad 8) -> 2-way-max banks
  __shared__ unsigned short Bs[128 * 40];
  int tid = threadIdx.x;
  int wave = tid >> 6, l = tid & 63;
  int n0 = blockIdx.x * 128, m0 = blockIdx.y * 128;
  int wm = (wave & 1) * 64, wn = (wave >> 1) * 64;
  int mrow = l & 15, quad = l >> 4;

  f32x4 acc[4][4];
#pragma unroll
  for (int i = 0; i < 4; i++)
#pragma unroll
    for (int jj = 0; jj < 4; jj++) acc[i][jj] = (f32x4)(0.f);

  int srow = tid >> 1, skh = (tid & 1) * 16;
  const unsigned short* Ag = A + (size_t)(m0 + srow) * K + skh;
  const unsigned short* Bg = Bm + (size_t)(n0 + srow) * K + skh;

  uint4 a0 = *(const uint4*)(Ag);
  uint4 a1 = *(const uint4*)(Ag + 8);
  uint4 b0 = *(const uint4*)(Bg);
  uint4 b1 = *(const uint4*)(Bg + 8);

  for (int k0 = 0; k0 < K; k0 += 32) {
    __syncthreads();
    *(uint4*)&As[srow * 40 + skh] = a0;
    *(uint4*)&As[srow * 40 + skh + 8] = a1;
    *(uint4*)&Bs[srow * 40 + skh] = b0;
    *(uint4*)&Bs[srow * 40 + skh + 8] = b1;
    __syncthreads();
    if (k0 + 32 < K) {                      // software prefetch next K-slab
      a0 = *(const uint4*)(Ag + k0 + 32);
      a1 = *(const uint4*)(Ag + k0 + 40);
      b0 = *(const uint4*)(Bg + k0 + 32);
      b1 = *(const uint4*)(Bg + k0 + 40);
    }
    bf16x8 af[4], bfr[4];
#pragma unroll
    for (int i = 0; i < 4; i++) {
      af[i]  = *(const bf16x8*)&As[(wm + i * 16 + mrow) * 40 + quad * 8];
      bfr[i] = *(const bf16x8*)&Bs[(wn + i * 16 + mrow) * 40 + quad * 8];
    }
#pragma unroll
    for (int i = 0; i < 4; i++)
#pragma unroll
      for (int jj = 0; jj < 4; jj++)
        acc[i][jj] = __builtin_amdgcn_mfma_f32_16x16x32_bf16(af[i], bfr[jj], acc[i][jj], 0, 0, 0);
  }

  // C/D layout: col = lane&15, row = quad*4 + reg  [verified m89/m91]
  int cn = l & 15;
#pragma unroll
  for (int jj = 0; jj < 4; jj++) {
    int n = n0 + wn + jj * 16 + cn;
    float bv = bias ? bias[n] : 0.f;
#pragma unroll
    for (int i = 0; i < 4; i++) {
      int mb = m0 + wm + i * 16 + quad * 4;
#pragma unroll
      for (int r = 0; r < 4; r++) {
        C[(size_t)(mb + r) * N + n] = acc[i][jj][r] + bv;
      }
    }
  }
}

extern "C" void kernel_launch(void* const* d_in, const int* in_sizes, int n_in,
                              void* d_out, int out_size, void* d_ws, size_t ws_size,
                              hipStream_t stream) {
  const float* encoder_out  = (const float*)d_in[0];
  const int*   encoder_lens = (const int*)d_in[1];
  const int*   decoder_in   = (const int*)d_in[2];
  const float* emb_table    = (const float*)d_in[3];
  const float* W_attn       = (const float*)d_in[4];
  const float* W_ih0        = (const float*)d_in[5];
  const float* W_hh0        = (const float*)d_in[6];
  const float* b_ih0        = (const float*)d_in[7];
  const float* b_hh0        = (const float*)d_in[8];
  const float* W_ih1        = (const float*)d_in[9];
  const float* W_hh1        = (const float*)d_in[10];
  const float* b_ih1        = (const float*)d_in[11];
  const float* b_hh1        = (const float*)d_in[12];
  const float* W_out        = (const float*)d_in[13];
  const float* b_out        = (const float*)d_in[14];
  float* out = (float*)d_out;

  // ws layout (floats): X[2,097,152] | hstate[65,536] | scores[16,384] | counter[16] | Xb | Wb
  float* X        = (float*)d_ws;
  float* hstate   = X + 2097152;
  float* scores   = hstate + 65536;
  unsigned* cnt   = (unsigned*)(scores + 16384);
  unsigned short* Xb = (unsigned short*)(scores + 16384 + 16);
  unsigned short* Wb = Xb + 2097152;
  const size_t need_bf16 = (size_t)(2097152 + 65536 + 16384 + 16) * 4 + (size_t)2097152 * 2 + (size_t)32768000 * 2;
  bool use_bf16 = ws_size >= need_bf16;

  // big loop-invariant temps in d_out head (fully overwritten by final GEMM)
  float* enc_proj = out;                 // 8,388,608 floats
  float* embedded = out + 8388608;       // 1,048,576 floats

  zero_counter<<<1, 64, 0, stream>>>(cnt);
  embed_kernel<<<B_ * U_, 128, 0, stream>>>(decoder_in, emb_table, embedded);
  gemm_abt<<<dim3(4, 128), 256, 0, stream>>>(encoder_out, W_attn, nullptr, enc_proj, 512, 512);

  recurrence<<<GRIDB, 256, 0, stream>>>(enc_proj, encoder_out, encoder_lens, embedded,
                                        W_ih0, W_hh0, b_ih0, b_hh0,
                                        W_ih1, W_hh1, b_ih1, b_hh1,
                                        X, scores, hstate, cnt);

  if (use_bf16) {
    f2bf<<<2048, 256, 0, stream>>>(X, Xb, 2097152);
    f2bf<<<32000, 256, 0, stream>>>(W_out, Wb, 32768000);
    gemm_bf16<<<dim3(250, 16), 256, 0, stream>>>(Xb, Wb, b_out, out, V_, 1024);
  } else {
    gemm_abt<<<dim3(250, 16), 256, 0, stream>>>(X, W_out, b_out, out, V_, 1024);
  }
}

// Round 3
// 11216.544 us; speedup vs baseline: 1.7383x; 1.7383x over previous
//
#include <hip/hip_runtime.h>
#include <math.h>

#define B_ 32
#define T_ 512
#define U_ 64
#define V_ 32000
#define H_ 512
#define E_ 512
#define GRIDB 512   // 2 blocks/CU on 256 CUs, co-resident by capacity

typedef __attribute__((ext_vector_type(8))) short bf16x8;
typedef __attribute__((ext_vector_type(4))) float f32x4;

__device__ __forceinline__ float dot4(float4 a, float4 b) {
  return a.x * b.x + a.y * b.y + a.z * b.z + a.w * b.w;
}

// ---------------- embedding gather ----------------
__global__ void embed_kernel(const int* __restrict__ tok, const float* __restrict__ table,
                             float* __restrict__ out) {
  int row = blockIdx.x;
  int t = tok[row];
  const float4* src = (const float4*)(table + (size_t)t * H_);
  float4* dst = (float4*)(out + (size_t)row * H_);
  dst[threadIdx.x] = src[threadIdx.x];
}

__global__ void zero_flags(unsigned* f) { f[blockIdx.x * 256 + threadIdx.x] = 0u; }

// ---------------- fp32 GEMM: C[m,n] = A[m,:lda] . Bm[n,:ldb] + bias[n] ----------------
__global__ __launch_bounds__(256) void gemm_abt(
    const float* __restrict__ A, int lda, const float* __restrict__ Bm, int ldb,
    const float* __restrict__ bias, float* __restrict__ C, int N, int K) {
  __shared__ float As[8][128];
  __shared__ float Bs[8][128];
  int tid = threadIdx.x;
  int n0 = blockIdx.x * 128, m0 = blockIdx.y * 128;
  int lr = tid >> 1;
  int lk = (tid & 1) * 4;
  const float* Ap = A + (size_t)(m0 + lr) * lda + lk;
  const float* Bp = Bm + (size_t)(n0 + lr) * ldb + lk;
  int tx = tid & 15, ty = tid >> 4;
  float acc[8][8];
#pragma unroll
  for (int i = 0; i < 8; i++)
#pragma unroll
    for (int j = 0; j < 8; j++) acc[i][j] = 0.f;

  for (int k0 = 0; k0 < K; k0 += 8) {
    float4 av = *(const float4*)(Ap + k0);
    float4 bv = *(const float4*)(Bp + k0);
    __syncthreads();
    As[lk + 0][lr] = av.x; As[lk + 1][lr] = av.y; As[lk + 2][lr] = av.z; As[lk + 3][lr] = av.w;
    Bs[lk + 0][lr] = bv.x; Bs[lk + 1][lr] = bv.y; Bs[lk + 2][lr] = bv.z; Bs[lk + 3][lr] = bv.w;
    __syncthreads();
#pragma unroll
    for (int kk = 0; kk < 8; kk++) {
      float a[8], b[8];
      *(float4*)&a[0] = *(const float4*)&As[kk][ty * 4];
      *(float4*)&a[4] = *(const float4*)&As[kk][ty * 4 + 64];
      *(float4*)&b[0] = *(const float4*)&Bs[kk][tx * 4];
      *(float4*)&b[4] = *(const float4*)&Bs[kk][tx * 4 + 64];
#pragma unroll
      for (int i = 0; i < 8; i++)
#pragma unroll
        for (int j = 0; j < 8; j++) acc[i][j] = fmaf(a[i], b[j], acc[i][j]);
    }
  }
  float bb[8] = {0, 0, 0, 0, 0, 0, 0, 0};
  if (bias) {
    *(float4*)&bb[0] = *(const float4*)&bias[n0 + tx * 4];
    *(float4*)&bb[4] = *(const float4*)&bias[n0 + tx * 4 + 64];
  }
#pragma unroll
  for (int i = 0; i < 8; i++) {
    int m = m0 + ty * 4 + (i & 3) + (i >> 2) * 64;
    float* Crow = C + (size_t)m * N + n0;
    *(float4*)(Crow + tx * 4) = make_float4(acc[i][0] + bb[0], acc[i][1] + bb[1], acc[i][2] + bb[2], acc[i][3] + bb[3]);
    *(float4*)(Crow + tx * 4 + 64) = make_float4(acc[i][4] + bb[4], acc[i][5] + bb[5], acc[i][6] + bb[6], acc[i][7] + bb[7]);
  }
}

// ---------------- grid barrier: arrive-flags + replicated go-flags, RMW spins ----------------
// RMW (fetch_add 0) executes at the coherence point -> immune to stale-L2 spin livelock.
__device__ __forceinline__ unsigned ld_coh(unsigned* p) {
  return __hip_atomic_fetch_add(p, 0u, __ATOMIC_RELAXED, __HIP_MEMORY_SCOPE_AGENT);
}

__device__ __forceinline__ void grid_bar(unsigned* arrive, unsigned* go,
                                         int bid, int tid, unsigned& gen) {
  gen++;
  __syncthreads();
  if (bid == 0) {
    for (int i = tid + 1; i < GRIDB; i += 256) {
      unsigned* slot = &arrive[i * 16];
      while (ld_coh(slot) < gen) __builtin_amdgcn_s_sleep(1);
    }
    __syncthreads();
    if (tid == 0) __threadfence();       // acquire (others' data) + release (for go)
    __syncthreads();
    if (tid < 64)
      __hip_atomic_exchange(&go[tid * 16], gen, __ATOMIC_RELAXED, __HIP_MEMORY_SCOPE_AGENT);
  } else {
    if (tid == 0) {
      __threadfence();                   // release my block's writes
      __hip_atomic_exchange(&arrive[bid * 16], gen, __ATOMIC_RELAXED, __HIP_MEMORY_SCOPE_AGENT);
      unsigned* g = &go[(bid & 63) * 16];
      while (ld_coh(g) < gen) __builtin_amdgcn_s_sleep(1);
      __threadfence();                   // acquire others' writes (inv L1/L2)
    }
    __syncthreads();
  }
}

// ---------------- persistent recurrence ----------------
__global__ __launch_bounds__(256, 2) void recurrence(
    const float* __restrict__ enc_proj, const float* __restrict__ enc_out,
    const int* __restrict__ lens, const float* __restrict__ embedded,
    const float* __restrict__ geb,       // [2048][1536] precomputed emb-half gates of GRU0
    const float* __restrict__ W_ih0, const float* __restrict__ W_hh0,
    const float* __restrict__ b_ih0, const float* __restrict__ b_hh0,
    const float* __restrict__ W_ih1, const float* __restrict__ W_hh1,
    const float* __restrict__ b_ih1, const float* __restrict__ b_hh1,
    float* __restrict__ X, float* __restrict__ scores,
    float* __restrict__ hstate, unsigned* __restrict__ arrive, unsigned* __restrict__ go) {
  int bid = blockIdx.x, tid = threadIdx.x;
  unsigned gen = 0;
  __shared__ float q[512];
  __shared__ float p[512];
  __shared__ float part[16];
  // step-invariant weights, loaded ONCE:
  __shared__ float Wcr[512], Wcz[512], Wcn[512];   // W_ih0 ctx half (cols 512..1023)
  __shared__ float Vr[512], Vz[512], Vn[512];      // W_hh0
  __shared__ float Ur[512], Uz[512], Un[512];      // W_ih1
  __shared__ float Tr[512], Tz[512], Tn[512];      // W_hh1

  float* h0 = hstate;             // [2][32][512]
  float* h1 = hstate + 32768;

  int j = bid;                    // GRU output unit
  // hoist weight loads (coalesced, once per kernel)
  for (int k = tid; k < 512; k += 256) {
    Wcr[k] = W_ih0[(size_t)j * 1024 + 512 + k];
    Wcz[k] = W_ih0[((size_t)j + 512) * 1024 + 512 + k];
    Wcn[k] = W_ih0[((size_t)j + 1024) * 1024 + 512 + k];
    Vr[k] = W_hh0[(size_t)j * 512 + k];
    Vz[k] = W_hh0[((size_t)j + 512) * 512 + k];
    Vn[k] = W_hh0[((size_t)j + 1024) * 512 + k];
    Ur[k] = W_ih1[(size_t)j * 512 + k];
    Uz[k] = W_ih1[((size_t)j + 512) * 512 + k];
    Un[k] = W_ih1[((size_t)j + 1024) * 512 + k];
    Tr[k] = W_hh1[(size_t)j * 512 + k];
    Tz[k] = W_hh1[((size_t)j + 512) * 512 + k];
    Tn[k] = W_hh1[((size_t)j + 1024) * 512 + k];
  }
  // zero hidden state
  int zi = bid * 256 + tid;
  if (zi < 65536) hstate[zi] = 0.f;

  int sb = bid >> 4;              // batch for S1/S2
  int schunk = bid & 15;          // t-chunk / e-chunk
  int len = lens[sb];
  float bir = b_ih0[j] + b_hh0[j], biz = b_ih0[512 + j] + b_hh0[512 + j];
  float bin = b_ih0[1024 + j], bhn = b_hh0[1024 + j];
  float cir = b_ih1[j] + b_hh1[j], ciz = b_ih1[512 + j] + b_hh1[512 + j];
  float cin = b_ih1[1024 + j], chn = b_hh1[1024 + j];

  grid_bar(arrive, go, bid, tid, gen);

  int w = tid >> 6, l = tid & 63;
  int s = tid & 7, bb = tid >> 3;

  for (int u = 0; u < U_; u++) {
    int cur = u & 1, nxt = cur ^ 1;
    float* h0c = h0 + cur * 16384; float* h0n = h0 + nxt * 16384;
    float* h1c = h1 + cur * 16384; float* h1n = h1 + nxt * 16384;

    // ---- S1: scores for t in [schunk*32, +32) ----
    {
      const float* qsrc = (u == 0) ? (embedded + (size_t)sb * U_ * H_) : (h1c + sb * H_);
      q[tid] = qsrc[tid]; q[tid + 256] = qsrc[tid + 256];
      __syncthreads();
#pragma unroll
      for (int i = 0; i < 8; i++) {
        int t = schunk * 32 + w * 8 + i;
        float acc = 0.f;
        if (t < len) {
          const float* row = enc_proj + ((size_t)sb * T_ + t) * H_;
#pragma unroll
          for (int jj = 0; jj < 8; jj++) acc = fmaf(row[l + 64 * jj], q[l + 64 * jj], acc);
#pragma unroll
          for (int off = 32; off; off >>= 1) acc += __shfl_xor(acc, off, 64);
        }
        if (l == 0) scores[sb * T_ + t] = (t < len) ? acc : -INFINITY;
      }
    }
    grid_bar(arrive, go, bid, tid, gen);

    // ---- S2: softmax (redundant per block) + context e-slice ----
    {
      float v1 = scores[sb * T_ + tid], v2 = scores[sb * T_ + 256 + tid];
      float m = fmaxf(v1, v2);
#pragma unroll
      for (int off = 32; off; off >>= 1) m = fmaxf(m, __shfl_xor(m, off, 64));
      if (l == 0) part[w] = m;
      __syncthreads();
      m = fmaxf(fmaxf(part[0], part[1]), fmaxf(part[2], part[3]));
      float e1 = __expf(v1 - m), e2 = __expf(v2 - m);
      float sm = e1 + e2;
#pragma unroll
      for (int off = 32; off; off >>= 1) sm += __shfl_xor(sm, off, 64);
      __syncthreads();
      if (l == 0) part[w] = sm;
      __syncthreads();
      float inv = 1.f / (part[0] + part[1] + part[2] + part[3]);
      p[tid] = e1 * inv; p[tid + 256] = e2 * inv;
      __syncthreads();
      int e = schunk * 32 + (tid & 31), ts = tid >> 5;
      float acc = 0.f;
      const float* eo = enc_out + (size_t)sb * T_ * E_ + e;
      for (int t = ts; t < len; t += 8) acc = fmaf(p[t], eo[(size_t)t * E_], acc);
      // reduce 8 t-slices: lanes with same (tid&31) across tid>>5 groups -> use LDS q[] scratch
      q[tid] = acc;
      __syncthreads();
      if (tid < 32) {
        float c = 0.f;
#pragma unroll
        for (int r = 0; r < 8; r++) c += q[tid + 32 * r];
        X[((size_t)sb * U_ + u) * 1024 + 512 + schunk * 32 + tid] = c;
      }
    }
    grid_bar(arrive, go, bid, tid, gen);

    // ---- S3: GRU0 unit j, all 32 batches; emb half precomputed in geb ----
    {
      const float* xc = X + ((size_t)bb * U_ + u) * 1024 + 512;
      const float* hp = h0c + bb * H_;
      float ar = 0, az = 0, ain = 0, ahn = 0;
#pragma unroll
      for (int i4 = 0; i4 < 16; i4++) {
        int k = s * 64 + 4 * ((i4 + 2 * s) & 15);    // bank-rotated
        float4 xv = *(const float4*)(xc + k);
        ar += dot4(*(const float4*)&Wcr[k], xv);
        az += dot4(*(const float4*)&Wcz[k], xv);
        ain += dot4(*(const float4*)&Wcn[k], xv);
        float4 hv = *(const float4*)(hp + k);
        ar += dot4(*(const float4*)&Vr[k], hv);
        az += dot4(*(const float4*)&Vz[k], hv);
        ahn += dot4(*(const float4*)&Vn[k], hv);
      }
#pragma unroll
      for (int off = 1; off < 8; off <<= 1) {
        ar += __shfl_xor(ar, off, 64); az += __shfl_xor(az, off, 64);
        ain += __shfl_xor(ain, off, 64); ahn += __shfl_xor(ahn, off, 64);
      }
      if (s == 0) {
        const float* ge = geb + ((size_t)bb * U_ + u) * 1536;
        float r = ar + ge[j] + bir;
        float z = az + ge[512 + j] + biz;
        float rg = 1.f / (1.f + __expf(-r));
        float zg = 1.f / (1.f + __expf(-z));
        float n = tanhf(ain + ge[1024 + j] + bin + rg * (ahn + bhn));
        h0n[bb * H_ + j] = (1.f - zg) * n + zg * hp[j];
      }
    }
    grid_bar(arrive, go, bid, tid, gen);

    // ---- S4: GRU1 unit j; writes h1n and X[:,0:512] ----
    {
      const float* xp = h0n + bb * H_;
      const float* hp = h1c + bb * H_;
      float ar = 0, az = 0, ain = 0, ahn = 0;
#pragma unroll
      for (int i4 = 0; i4 < 16; i4++) {
        int k = s * 64 + 4 * ((i4 + 2 * s) & 15);
        float4 xv = *(const float4*)(xp + k);
        ar += dot4(*(const float4*)&Ur[k], xv);
        az += dot4(*(const float4*)&Uz[k], xv);
        ain += dot4(*(const float4*)&Un[k], xv);
        float4 hv = *(const float4*)(hp + k);
        ar += dot4(*(const float4*)&Tr[k], hv);
        az += dot4(*(const float4*)&Tz[k], hv);
        ahn += dot4(*(const float4*)&Tn[k], hv);
      }
#pragma unroll
      for (int off = 1; off < 8; off <<= 1) {
        ar += __shfl_xor(ar, off, 64); az += __shfl_xor(az, off, 64);
        ain += __shfl_xor(ain, off, 64); ahn += __shfl_xor(ahn, off, 64);
      }
      if (s == 0) {
        float r = ar + cir;
        float z = az + ciz;
        float rg = 1.f / (1.f + __expf(-r));
        float zg = 1.f / (1.f + __expf(-z));
        float n = tanhf(ain + cin + rg * (ahn + chn));
        float ho = (1.f - zg) * n + zg * hp[j];
        h1n[bb * H_ + j] = ho;
        X[((size_t)bb * U_ + u) * 1024 + j] = ho;
      }
    }
    grid_bar(arrive, go, bid, tid, gen);
  }
}

// ---------------- fp32 -> bf16 (RNE) ----------------
__device__ __forceinline__ unsigned short cvt_bf(float f) {
  unsigned int x = __float_as_uint(f);
  unsigned int r = x + 0x7fffu + ((x >> 16) & 1u);
  return (unsigned short)(r >> 16);
}

__global__ __launch_bounds__(256) void f2bf(const float* __restrict__ in,
                                            unsigned short* __restrict__ out, int n) {
  int i = 4 * (blockIdx.x * 256 + threadIdx.x);
  if (i < n) {
    float4 v = *(const float4*)(in + i);
    ushort4 o;
    o.x = cvt_bf(v.x); o.y = cvt_bf(v.y); o.z = cvt_bf(v.z); o.w = cvt_bf(v.w);
    *(ushort4*)(out + i) = o;
  }
}

// ---------------- bf16 MFMA GEMM (logits) ----------------
__global__ __launch_bounds__(256) void gemm_bf16(
    const unsigned short* __restrict__ A, const unsigned short* __restrict__ Bm,
    const float* __restrict__ bias, float* __restrict__ C, int N, int K) {
  __shared__ unsigned short As[128 * 40];
  __shared__ unsigned short Bs[128 * 40];
  int tid = threadIdx.x;
  int wave = tid >> 6, l = tid & 63;
  int n0 = blockIdx.x * 128, m0 = blockIdx.y * 128;
  int wm = (wave & 1) * 64, wn = (wave >> 1) * 64;
  int mrow = l & 15, quad = l >> 4;

  f32x4 acc[4][4];
#pragma unroll
  for (int i = 0; i < 4; i++)
#pragma unroll
    for (int jj = 0; jj < 4; jj++) acc[i][jj] = (f32x4)(0.f);

  int srow = tid >> 1, skh = (tid & 1) * 16;
  const unsigned short* Ag = A + (size_t)(m0 + srow) * K + skh;
  const unsigned short* Bg = Bm + (size_t)(n0 + srow) * K + skh;

  uint4 a0 = *(const uint4*)(Ag);
  uint4 a1 = *(const uint4*)(Ag + 8);
  uint4 b0 = *(const uint4*)(Bg);
  uint4 b1 = *(const uint4*)(Bg + 8);

  for (int k0 = 0; k0 < K; k0 += 32) {
    __syncthreads();
    *(uint4*)&As[srow * 40 + skh] = a0;
    *(uint4*)&As[srow * 40 + skh + 8] = a1;
    *(uint4*)&Bs[srow * 40 + skh] = b0;
    *(uint4*)&Bs[srow * 40 + skh + 8] = b1;
    __syncthreads();
    if (k0 + 32 < K) {
      a0 = *(const uint4*)(Ag + k0 + 32);
      a1 = *(const uint4*)(Ag + k0 + 40);
      b0 = *(const uint4*)(Bg + k0 + 32);
      b1 = *(const uint4*)(Bg + k0 + 40);
    }
    bf16x8 af[4], bfr[4];
#pragma unroll
    for (int i = 0; i < 4; i++) {
      af[i]  = *(const bf16x8*)&As[(wm + i * 16 + mrow) * 40 + quad * 8];
      bfr[i] = *(const bf16x8*)&Bs[(wn + i * 16 + mrow) * 40 + quad * 8];
    }
#pragma unroll
    for (int i = 0; i < 4; i++)
#pragma unroll
      for (int jj = 0; jj < 4; jj++)
        acc[i][jj] = __builtin_amdgcn_mfma_f32_16x16x32_bf16(af[i], bfr[jj], acc[i][jj], 0, 0, 0);
  }

  int cn = l & 15;
#pragma unroll
  for (int jj = 0; jj < 4; jj++) {
    int n = n0 + wn + jj * 16 + cn;
    float bv = bias ? bias[n] : 0.f;
#pragma unroll
    for (int i = 0; i < 4; i++) {
      int mb = m0 + wm + i * 16 + quad * 4;
#pragma unroll
      for (int r = 0; r < 4; r++) {
        C[(size_t)(mb + r) * N + n] = acc[i][jj][r] + bv;
      }
    }
  }
}

extern "C" void kernel_launch(void* const* d_in, const int* in_sizes, int n_in,
                              void* d_out, int out_size, void* d_ws, size_t ws_size,
                              hipStream_t stream) {
  const float* encoder_out  = (const float*)d_in[0];
  const int*   encoder_lens = (const int*)d_in[1];
  const int*   decoder_in   = (const int*)d_in[2];
  const float* emb_table    = (const float*)d_in[3];
  const float* W_attn       = (const float*)d_in[4];
  const float* W_ih0        = (const float*)d_in[5];
  const float* W_hh0        = (const float*)d_in[6];
  const float* b_ih0        = (const float*)d_in[7];
  const float* b_hh0        = (const float*)d_in[8];
  const float* W_ih1        = (const float*)d_in[9];
  const float* W_hh1        = (const float*)d_in[10];
  const float* b_ih1        = (const float*)d_in[11];
  const float* b_hh1        = (const float*)d_in[12];
  const float* W_out        = (const float*)d_in[13];
  const float* b_out        = (const float*)d_in[14];
  float* out = (float*)d_out;

  // ws layout (4B units): X[2097152] | hstate[65536] | scores[16384] | flags[16384] | Xb | Wb
  float* X        = (float*)d_ws;
  float* hstate   = X + 2097152;
  float* scores   = hstate + 65536;
  unsigned* flags = (unsigned*)(scores + 16384);     // arrive: 512*16, go: 64*16
  unsigned* arrive = flags;
  unsigned* go     = flags + 512 * 16;
  unsigned short* Xb = (unsigned short*)(flags + 16384);
  unsigned short* Wb = Xb + 2097152;
  const size_t need_bf16 = (size_t)(2097152 + 65536 + 16384 + 16384) * 4 + (size_t)2097152 * 2 + (size_t)32768000 * 2;
  bool use_bf16 = ws_size >= need_bf16;

  // loop-invariant temps in d_out head (dead before final GEMM overwrites everything)
  float* enc_proj = out;                   // 8,388,608 floats
  float* embedded = out + 8388608;         // 1,048,576 floats
  float* geb      = out + 9437184;         // 3,145,728 floats: GRU0 emb-half gates

  zero_flags<<<64, 256, 0, stream>>>(flags);
  embed_kernel<<<B_ * U_, 128, 0, stream>>>(decoder_in, emb_table, embedded);
  // enc_proj[b,t,h]
  gemm_abt<<<dim3(4, 128), 256, 0, stream>>>(encoder_out, 512, W_attn, 512, nullptr, enc_proj, 512, 512);
  // geb[row, gate*512+j] = emb_row . W_ih0[gate*512+j][0:512]
  gemm_abt<<<dim3(12, 16), 256, 0, stream>>>(embedded, 512, W_ih0, 1024, nullptr, geb, 1536, 512);

  recurrence<<<GRIDB, 256, 0, stream>>>(enc_proj, encoder_out, encoder_lens, embedded, geb,
                                        W_ih0, W_hh0, b_ih0, b_hh0,
                                        W_ih1, W_hh1, b_ih1, b_hh1,
                                        X, scores, hstate, arrive, go);

  if (use_bf16) {
    f2bf<<<2048, 256, 0, stream>>>(X, Xb, 2097152);
    f2bf<<<32000, 256, 0, stream>>>(W_out, Wb, 32768000);
    gemm_bf16<<<dim3(250, 16), 256, 0, stream>>>(Xb, Wb, b_out, out, V_, 1024);
  } else {
    gemm_abt<<<dim3(250, 16), 256, 0, stream>>>(X, 1024, W_out, 1024, b_out, out, V_, 1024);
  }
}